// Round 3
// baseline (428.701 us; speedup 1.0000x reference)
//
#include <hip/hip_runtime.h>
#include <math.h>

#define RPB 4   // rays per block, one 64-lane wave per ray; all per-ray LDS is wave-private

// Wave-local LDS ordering: per-ray LDS is touched only by its own wave.
__device__ __forceinline__ void wave_fence() {
    asm volatile("s_waitcnt lgkmcnt(0)" ::: "memory");
    __builtin_amdgcn_wave_barrier();
}

// DPP helper: dest = (src lane valid) ? src[perm] : ident   (bound_ctrl=false keeps old)
template<int CTRL, int RMASK>
__device__ __forceinline__ float dpp_f(float ident, float x) {
    return __int_as_float(__builtin_amdgcn_update_dpp(
        __float_as_int(ident), __float_as_int(x), CTRL, RMASK, 0xF, false));
}
// DPP ctrl codes (GFX9/CDNA): row_shr:1/2/4/8 = 0x111/0x112/0x114/0x118,
// row_bcast15 = 0x142, row_bcast31 = 0x143, wave_shl1 = 0x130 (lane i <- i+1),
// wave_shr1 = 0x138 (lane i <- i-1).

__device__ __forceinline__ float sigmoid_(float x) {
    return __fdividef(1.0f, 1.0f + __expf(-x));
}

__device__ __forceinline__ float sdf_at(float ox, float oy, float oz,
                                        float dx, float dy, float dz, float t) {
    float px = fminf(fmaxf(ox + dx * t, -1.f), 1.f);
    float py = fminf(fmaxf(oy + dy * t, -1.f), 1.f);
    float pz = fminf(fmaxf(oz + dz * t, -1.f), 1.f);
    return sqrtf(px * px + py * py + pz * pz) - 0.5f;
}

// #{j in [0,32): (2j+1)/64 < c} = clamp(ceil(32c - 0.5), 0, 32)
__device__ __forceinline__ int m32(float c) {
    int v = (int)ceilf(fmaf(c, 32.0f, -0.5f));
    return v < 0 ? 0 : (v > 32 ? 32 : v);
}

template<int IT>
__device__ __forceinline__ void run_iter(float* __restrict__ z, float* __restrict__ s,
                                         float* __restrict__ outr, const int lane,
                                         const float ox, const float oy, const float ozr,
                                         const float dx, const float dy, const float dz)
{
    constexpr int  N = 128 + 32 * IT;   // current element count
    constexpr int  M = N - 1;           // interval count
    constexpr int  R = (M + 63) >> 6;   // elements/intervals per lane: 2,3,3,4
    constexpr bool LAST = (IT == 3);
    const float inv_s = (float)(64 << IT);
    const int k0 = lane * R;

    // ---- load owned elements (blocked, vectorized; OOB lanes read in-array garbage, guarded) ----
    float ez[R], es[R];
    if constexpr (R == 2) {
        float2 v = *(const float2*)(z + k0); ez[0] = v.x; ez[1] = v.y;
        float2 u = *(const float2*)(s + k0); es[0] = u.x; es[1] = u.y;
    } else if constexpr (R == 4) {
        float4 v = *(const float4*)(z + k0); ez[0] = v.x; ez[1] = v.y; ez[2] = v.z; ez[3] = v.w;
        float4 u = *(const float4*)(s + k0); es[0] = u.x; es[1] = u.y; es[2] = u.z; es[3] = u.w;
    } else {
        #pragma unroll
        for (int r = 0; r < R; ++r) { ez[r] = z[k0 + r]; es[r] = s[k0 + r]; }
    }

    // neighbor elements via DPP wave shifts (no LDS)
    const float zend = dpp_f<0x130, 0xF>(0.f, ez[0]);       // z[k0+R]
    const float send = dpp_f<0x130, 0xF>(0.f, es[0]);
    const float zprv = dpp_f<0x138, 0xF>(0.f, ez[R - 1]);   // z[k0-1]
    const float sprv = dpp_f<0x138, 0xF>(0.f, es[R - 1]);

    // ---- alpha per owned interval ----
    float a_[R], q_[R];
    #pragma unroll
    for (int r = 0; r < R; ++r) {
        const int  k  = k0 + r;
        const bool iv = (k < M);
        const float zk  = ez[r], sk = es[r];
        const float zk1 = (r == R - 1) ? zend : ez[(r + 1) % R];
        const float sk1 = (r == R - 1) ? send : es[(r + 1) % R];
        const float zm  = (r == 0) ? zprv : ez[(r + R - 1) % R];
        const float sm  = (r == 0) ? sprv : es[(r + R - 1) % R];
        const float d01  = zk1 - zk;
        const float cosk = __fdividef(sk1 - sk, d01 + 1e-5f);
        const float cosp = (k > 0) ? __fdividef(sk - sm, zk - zm + 1e-5f) : 0.0f;
        float cv = fminf(fminf(cosp, cosk), 0.0f);
        cv = fmaxf(cv, -1000.0f);
        const float mid = 0.5f * (sk + sk1);
        const float hd  = 0.5f * d01;
        const float pc  = sigmoid_((mid - cv * hd) * inv_s);
        const float nc  = sigmoid_((mid + cv * hd) * inv_s);
        const float al  = __fdividef(pc - nc + 1e-5f, pc + 1e-5f);
        a_[r] = iv ? al : 0.0f;
        q_[r] = iv ? (1.0f - al + 1e-7f) : 1.0f;
    }

    // ---- exclusive transmittance cumprod (DPP wave scan) ----
    float P = q_[0];
    #pragma unroll
    for (int r = 1; r < R; ++r) P *= q_[r];
    float incP = P;
    incP *= dpp_f<0x111, 0xF>(1.f, incP);
    incP *= dpp_f<0x112, 0xF>(1.f, incP);
    incP *= dpp_f<0x114, 0xF>(1.f, incP);
    incP *= dpp_f<0x118, 0xF>(1.f, incP);
    incP *= dpp_f<0x142, 0xA>(1.f, incP);
    incP *= dpp_f<0x143, 0xC>(1.f, incP);
    float T = dpp_f<0x138, 0xF>(1.f, incP);   // exclusive start per lane

    // ---- weights + exclusive sum scan -> per-element cdf in registers ----
    float wv_[R];
    float L = 0.f;
    #pragma unroll
    for (int r = 0; r < R; ++r) {
        const bool iv = (k0 + r < M);
        wv_[r] = iv ? (a_[r] * T + 1e-5f) : 0.f;
        L += wv_[r];
        T *= q_[r];
    }
    float incL = L;
    incL += dpp_f<0x111, 0xF>(0.f, incL);
    incL += dpp_f<0x112, 0xF>(0.f, incL);
    incL += dpp_f<0x114, 0xF>(0.f, incL);
    incL += dpp_f<0x118, 0xF>(0.f, incL);
    incL += dpp_f<0x142, 0xA>(0.f, incL);
    incL += dpp_f<0x143, 0xC>(0.f, incL);
    const float S    = __shfl(incL, 63, 64);
    const float excL = dpp_f<0x138, 0xF>(0.f, incL);
    const float invS = 1.0f / S;

    float cdfe[R];   // cdf[k0+r]
    int   cm[R];     // #{new samples with u < cdf[k0+r]} == shift of old elem / sample range lo
    float run = excL;
    #pragma unroll
    for (int r = 0; r < R; ++r) {
        cdfe[r] = run * invS;
        cm[r]   = m32(cdfe[r]);
        run += wv_[r];
    }
    const float cdfend = dpp_f<0x130, 0xF>(1.f, cdfe[0]);   // cdf[k0+R]
    const int   cmend  = __builtin_amdgcn_update_dpp(32, cm[0], 0x130, 0xF, 0xF, false);

    // ---- scatter old elements: position = k + #{new before it} (closed form) ----
    #pragma unroll
    for (int r = 0; r < R; ++r) {
        const int k = k0 + r;
        if (k < N) {
            const int p = k + cm[r];
            if constexpr (LAST) { outr[p] = ez[r]; }
            else                { z[p] = ez[r]; s[p] = es[r]; }
        }
    }

    // ---- generate + place new samples owned by my intervals ----
    #pragma unroll
    for (int r = 0; r < R; ++r) {
        const int k = k0 + r;
        if (k < M) {
            const int jlo = cm[r];
            const int jhi = (r == R - 1) ? cmend : cm[(r + 1) % R];
            if (jhi > jlo) {
                const float cl = cdfe[r];
                const float ch = (r == R - 1) ? cdfend : cdfe[(r + 1) % R];
                float denom = ch - cl;
                denom = (denom < 1e-5f) ? 1.0f : denom;
                const float invd = __fdividef(1.0f, denom);
                const float zk   = ez[r];
                const float zk1  = (r == R - 1) ? zend : ez[(r + 1) % R];
                const float dz01 = zk1 - zk;
                for (int j = jlo; j < jhi; ++j) {
                    const float u  = (float)(2 * j + 1) * 0.015625f;
                    const float nz = zk + ((u - cl) * invd) * dz01;
                    const int pos = k + 1 + j;   // rank among old + stable index among new
                    if constexpr (LAST) { outr[pos] = nz; }
                    else {
                        z[pos] = nz;
                        s[pos] = sdf_at(ox, oy, ozr, dx, dy, dz, nz);
                    }
                }
            }
        }
    }
    if constexpr (!LAST) wave_fence();
}

__global__ __launch_bounds__(RPB * 64) void neus_kernel(
    const float* __restrict__ rays_o, const float* __restrict__ rays_d,
    float* __restrict__ out, int nrays)
{
    __shared__ __align__(16) float zS[RPB][260];
    __shared__ __align__(16) float sS[RPB][260];

    const int w    = threadIdx.x >> 6;
    const int lane = threadIdx.x & 63;
    const int ray  = blockIdx.x * RPB + w;
    if (ray >= nrays) return;   // safe: no block-wide barriers anywhere

    float* z = zS[w];
    float* s = sS[w];

    const float ox = rays_o[ray * 3 + 0], oy = rays_o[ray * 3 + 1], ozr = rays_o[ray * 3 + 2];
    float rx = rays_d[ray * 3 + 0], ry = rays_d[ray * 3 + 1], rz = rays_d[ray * 3 + 2];
    float inv = __fdividef(1.0f, sqrtf(rx * rx + ry * ry + rz * rz) + 1e-8f);
    const float dx = rx * inv, dy = ry * inv, dz = rz * inv;

    // init: z = 0.2 + 1.8*linspace(0,1,128), sdf at clipped points
    #pragma unroll
    for (int h = 0; h < 2; ++h) {
        const int k = lane + 64 * h;
        const float zv = 0.2f + 1.8f * ((float)k * (1.0f / 127.0f));
        z[k] = zv;
        s[k] = sdf_at(ox, oy, ozr, dx, dy, dz, zv);
    }
    wave_fence();

    float* outr = out + (size_t)ray * 256;
    run_iter<0>(z, s, outr, lane, ox, oy, ozr, dx, dy, dz);
    run_iter<1>(z, s, outr, lane, ox, oy, ozr, dx, dy, dz);
    run_iter<2>(z, s, outr, lane, ox, oy, ozr, dx, dy, dz);
    run_iter<3>(z, s, outr, lane, ox, oy, ozr, dx, dy, dz);
}

extern "C" void kernel_launch(void* const* d_in, const int* in_sizes, int n_in,
                              void* d_out, int out_size, void* d_ws, size_t ws_size,
                              hipStream_t stream) {
    const float* rays_o = (const float*)d_in[0];
    const float* rays_d = (const float*)d_in[1];
    float* out = (float*)d_out;
    const int nrays = in_sizes[0] / 3;
    const int blocks = (nrays + RPB - 1) / RPB;
    neus_kernel<<<blocks, RPB * 64, 0, stream>>>(rays_o, rays_d, out, nrays);
}

// Round 4
// 164.457 us; speedup vs baseline: 2.6068x; 2.6068x over previous
//
#include <hip/hip_runtime.h>
#include <math.h>

#define RPB 4   // rays per block, one 64-lane wave per ray; all per-ray LDS is wave-private

// Wave-local LDS ordering: per-ray LDS is touched only by its own wave.
__device__ __forceinline__ void wave_fence() {
    asm volatile("s_waitcnt lgkmcnt(0)" ::: "memory");
    __builtin_amdgcn_wave_barrier();
}

// DPP helpers: dest = src[perm] where valid, else ident (bound_ctrl=false keeps old).
// ctrl: row_shr:1/2/4/8 = 0x111/0x112/0x114/0x118, row_bcast15 = 0x142,
// row_bcast31 = 0x143, wave_shl1 = 0x130 (lane i <- i+1), wave_shr1 = 0x138 (i <- i-1).
template<int CTRL, int RMASK>
__device__ __forceinline__ float dpp_f(float ident, float x) {
    return __int_as_float(__builtin_amdgcn_update_dpp(
        __float_as_int(ident), __float_as_int(x), CTRL, RMASK, 0xF, false));
}
template<int CTRL, int RMASK>
__device__ __forceinline__ int dpp_i(int ident, int x) {
    return __builtin_amdgcn_update_dpp(ident, x, CTRL, RMASK, 0xF, false);
}

__device__ __forceinline__ float sigmoid_(float x) {
    return __fdividef(1.0f, 1.0f + __expf(-x));
}

__device__ __forceinline__ float zof(int k) {   // iter-0 analytic z grid
    return 0.2f + 1.8f * ((float)k * (1.0f / 127.0f));
}

struct Ray { float ox, oy, oz, dx, dy, dz; };

__device__ __forceinline__ float sdf_at(const Ray& rr, float t) {
    float px = fminf(fmaxf(rr.ox + rr.dx * t, -1.f), 1.f);
    float py = fminf(fmaxf(rr.oy + rr.dy * t, -1.f), 1.f);
    float pz = fminf(fmaxf(rr.oz + rr.dz * t, -1.f), 1.f);
    return sqrtf(px * px + py * py + pz * pz) - 0.5f;
}

// #{j in [0,32): (2j+1)/64 < c} = clamp(ceil(32c - 0.5), 0, 32)
__device__ __forceinline__ int m32(float c) {
    int v = (int)ceilf(fmaf(c, 32.0f, -0.5f));
    return v < 0 ? 0 : (v > 32 ? 32 : v);
}

template<int IT>
__device__ __forceinline__ void run_iter(float* __restrict__ z, float* __restrict__ s,
                                         float* __restrict__ cdf, int* __restrict__ sampK,
                                         float* __restrict__ outr, const int lane, const Ray rr)
{
    constexpr int  N = 128 + 32 * IT;   // current element count
    constexpr int  M = N - 1;           // interval count
    constexpr int  R = (M + 63) >> 6;   // per-lane elements: 2,3,3,4
    constexpr bool LAST  = (IT == 3);
    constexpr bool FIRST = (IT == 0);
    const float inv_s = (float)(64 << IT);
    const int k0 = lane * R;

    // ---- owned elements + neighbors (analytic on iter 0; LDS otherwise) ----
    float ez[R], es[R], zend, send, zprv, sprv;
    if constexpr (FIRST) {
        #pragma unroll
        for (int r = 0; r < R; ++r) { ez[r] = zof(k0 + r); es[r] = sdf_at(rr, ez[r]); }
        zend = zof(k0 + R);  send = sdf_at(rr, zend);
        zprv = zof(k0 - 1);  sprv = sdf_at(rr, zprv);
    } else {
        if constexpr (R == 2) {
            float2 v = *(const float2*)(z + k0); ez[0] = v.x; ez[1] = v.y;
            float2 u = *(const float2*)(s + k0); es[0] = u.x; es[1] = u.y;
        } else if constexpr (R == 4) {
            float4 v = *(const float4*)(z + k0); ez[0]=v.x; ez[1]=v.y; ez[2]=v.z; ez[3]=v.w;
            float4 u = *(const float4*)(s + k0); es[0]=u.x; es[1]=u.y; es[2]=u.z; es[3]=u.w;
        } else {
            #pragma unroll
            for (int r = 0; r < R; ++r) { ez[r] = z[k0 + r]; es[r] = s[k0 + r]; }
        }
        zend = dpp_f<0x130, 0xF>(0.f, ez[0]);
        send = dpp_f<0x130, 0xF>(0.f, es[0]);
        zprv = dpp_f<0x138, 0xF>(0.f, ez[R - 1]);
        sprv = dpp_f<0x138, 0xF>(0.f, es[R - 1]);
    }

    // ---- cos_val once per interval; prev_cos by roll (matches reference) ----
    float ck[R];
    #pragma unroll
    for (int r = 0; r < R; ++r) {
        const float zk1 = (r == R - 1) ? zend : ez[(r + 1) % R];
        const float sk1 = (r == R - 1) ? send : es[(r + 1) % R];
        ck[r] = __fdividef(sk1 - es[r], zk1 - ez[r] + 1e-5f);
    }
    const float ckprv = dpp_f<0x138, 0xF>(0.f, ck[R - 1]);  // lane0 -> 0 (k=0 case)

    // ---- alpha per interval ----
    float a_[R], q_[R];
    #pragma unroll
    for (int r = 0; r < R; ++r) {
        const int  k  = k0 + r;
        const bool iv = (k < M);
        const float zk1 = (r == R - 1) ? zend : ez[(r + 1) % R];
        const float sk1 = (r == R - 1) ? send : es[(r + 1) % R];
        const float cosp = (r == 0) ? ckprv : ck[r - 1];
        float cv = fminf(fminf(cosp, ck[r]), 0.0f);
        cv = fmaxf(cv, -1000.0f);
        const float mid = 0.5f * (es[r] + sk1);
        const float hd  = 0.5f * (zk1 - ez[r]);
        const float pc  = sigmoid_((mid - cv * hd) * inv_s);
        const float nc  = sigmoid_((mid + cv * hd) * inv_s);
        const float al  = __fdividef(pc - nc + 1e-5f, pc + 1e-5f);
        a_[r] = iv ? al : 0.0f;
        q_[r] = iv ? (1.0f - al + 1e-7f) : 1.0f;
    }

    // ---- exclusive transmittance cumprod (DPP wave scan, pure VALU) ----
    float P = q_[0];
    #pragma unroll
    for (int r = 1; r < R; ++r) P *= q_[r];
    float incP = P;
    incP *= dpp_f<0x111, 0xF>(1.f, incP);
    incP *= dpp_f<0x112, 0xF>(1.f, incP);
    incP *= dpp_f<0x114, 0xF>(1.f, incP);
    incP *= dpp_f<0x118, 0xF>(1.f, incP);
    incP *= dpp_f<0x142, 0xA>(1.f, incP);
    incP *= dpp_f<0x143, 0xC>(1.f, incP);
    float T = dpp_f<0x138, 0xF>(1.f, incP);

    // ---- weights + exclusive sum scan -> cdf in registers ----
    float wv_[R], L = 0.f;
    #pragma unroll
    for (int r = 0; r < R; ++r) {
        const bool iv = (k0 + r < M);
        wv_[r] = iv ? (a_[r] * T + 1e-5f) : 0.f;
        L += wv_[r];
        T *= q_[r];
    }
    float incL = L;
    incL += dpp_f<0x111, 0xF>(0.f, incL);
    incL += dpp_f<0x112, 0xF>(0.f, incL);
    incL += dpp_f<0x114, 0xF>(0.f, incL);
    incL += dpp_f<0x118, 0xF>(0.f, incL);
    incL += dpp_f<0x142, 0xA>(0.f, incL);
    incL += dpp_f<0x143, 0xC>(0.f, incL);
    const float S    = __shfl(incL, 63, 64);
    const float excL = dpp_f<0x138, 0xF>(0.f, incL);
    const float invS = 1.0f / S;

    float cdfe[R];   // cdf[k0+r]
    int   cm[R];     // #{samples with u < cdf[k0+r]} = shift of old elem k0+r
    float run = excL;
    #pragma unroll
    for (int r = 0; r < R; ++r) {
        cdfe[r] = run * invS;
        cm[r]   = m32(cdfe[r]);
        run += wv_[r];
    }
    const float cdfend = dpp_f<0x130, 0xF>(1.f, cdfe[0]);
    const int   cmend  = dpp_i<0x130, 0xF>(32, cm[0]);
    (void)cdfend;

    // ---- publish cdf (vectorized) + run-start marks (one store per nonempty interval) ----
    if constexpr (R == 2) {
        *(float2*)(cdf + k0) = make_float2(cdfe[0], cdfe[1]);
    } else if constexpr (R == 4) {
        *(float4*)(cdf + k0) = make_float4(cdfe[0], cdfe[1], cdfe[2], cdfe[3]);
    } else {
        #pragma unroll
        for (int r = 0; r < R; ++r) cdf[k0 + r] = cdfe[r];
    }
    #pragma unroll
    for (int r = 0; r < R; ++r) {
        const int k   = k0 + r;
        const int jlo = cm[r];
        const int jhi = (r == R - 1) ? cmend : cm[(r + 1) % R];
        if (k < M && jhi > jlo) sampK[jlo] = k;   // distinct jlo across nonempty intervals
    }
    wave_fence();   // marks+cdf visible before gather

    // ---- lane-parallel sampling: DPP max-scan inverts marks -> interval per sample ----
    float nz = 0.f, ns = 0.f; int pos = 0;
    const bool have = (lane < 32);
    if (have) {
        int m = sampK[lane];
        m = max(m, dpp_i<0x111, 0xF>(-1, m));
        m = max(m, dpp_i<0x112, 0xF>(-1, m));
        m = max(m, dpp_i<0x114, 0xF>(-1, m));
        m = max(m, dpp_i<0x118, 0xF>(-1, m));
        m = max(m, dpp_i<0x142, 0xA>(-1, m));
        const int kk = m;
        const float cl = cdf[kk], ch = cdf[kk + 1];
        float zk, zk1;
        if constexpr (FIRST) { zk = zof(kk); zk1 = zof(kk + 1); }
        else                 { zk = z[kk];   zk1 = z[kk + 1];   }
        float denom = ch - cl;
        denom = (denom < 1e-5f) ? 1.0f : denom;
        const float u = (float)(2 * lane + 1) * 0.015625f;
        nz  = zk + __fdividef(u - cl, denom) * (zk1 - zk);
        pos = kk + 1 + lane;   // rank among old + stable index among new
        if constexpr (!LAST) ns = sdf_at(rr, nz);
    }
    if constexpr (!LAST) wave_fence();   // gather reads drained before in-place scatter

    // ---- scatter old (closed-form shift) + place new ----
    #pragma unroll
    for (int r = 0; r < R; ++r) {
        const int k = k0 + r;
        if (k < N) {
            const int p = k + cm[r];
            if constexpr (LAST) { outr[p] = ez[r]; }
            else                { z[p] = ez[r]; s[p] = es[r]; }
        }
    }
    if (have) {
        if constexpr (LAST) { outr[pos] = nz; }
        else                { z[pos] = nz; s[pos] = ns; }
    }
    if constexpr (!LAST) {
        if (have) sampK[lane] = -1;   // re-init marks for next iteration
        wave_fence();
    }
}

__global__ __launch_bounds__(RPB * 64) void neus_kernel(
    const float* __restrict__ rays_o, const float* __restrict__ rays_d,
    float* __restrict__ out, int nrays)
{
    __shared__ __align__(16) float zS[RPB][256];
    __shared__ __align__(16) float sS[RPB][256];
    __shared__ __align__(16) float cdfS[RPB][256];
    __shared__ __align__(16) int   kS[RPB][32];

    const int w    = threadIdx.x >> 6;
    const int lane = threadIdx.x & 63;
    const int ray  = blockIdx.x * RPB + w;
    if (ray >= nrays) return;   // safe: no block-wide barriers anywhere

    float* z    = zS[w];
    float* s    = sS[w];
    float* cdf  = cdfS[w];
    int*   samp = kS[w];

    Ray rr;
    rr.ox = rays_o[ray * 3 + 0]; rr.oy = rays_o[ray * 3 + 1]; rr.oz = rays_o[ray * 3 + 2];
    float rx = rays_d[ray * 3 + 0], ry = rays_d[ray * 3 + 1], rz = rays_d[ray * 3 + 2];
    float inv = __fdividef(1.0f, sqrtf(rx * rx + ry * ry + rz * rz) + 1e-8f);
    rr.dx = rx * inv; rr.dy = ry * inv; rr.dz = rz * inv;

    if (lane < 32) samp[lane] = -1;
    wave_fence();

    float* outr = out + (size_t)ray * 256;
    run_iter<0>(z, s, cdf, samp, outr, lane, rr);
    run_iter<1>(z, s, cdf, samp, outr, lane, rr);
    run_iter<2>(z, s, cdf, samp, outr, lane, rr);
    run_iter<3>(z, s, cdf, samp, outr, lane, rr);
}

extern "C" void kernel_launch(void* const* d_in, const int* in_sizes, int n_in,
                              void* d_out, int out_size, void* d_ws, size_t ws_size,
                              hipStream_t stream) {
    const float* rays_o = (const float*)d_in[0];
    const float* rays_d = (const float*)d_in[1];
    float* out = (float*)d_out;
    const int nrays = in_sizes[0] / 3;
    const int blocks = (nrays + RPB - 1) / RPB;
    neus_kernel<<<blocks, RPB * 64, 0, stream>>>(rays_o, rays_d, out, nrays);
}

// Round 5
// 131.123 us; speedup vs baseline: 3.2695x; 1.2542x over previous
//
#include <hip/hip_runtime.h>
#include <math.h>

#define RPB 4   // rays per block, one 64-lane wave per ray; all per-ray LDS is wave-private

// Wave-local LDS ordering: per-ray LDS is touched only by its own wave.
__device__ __forceinline__ void wave_fence() {
    asm volatile("s_waitcnt lgkmcnt(0)" ::: "memory");
    __builtin_amdgcn_wave_barrier();
}

// DPP helpers: dest = src[perm] where valid, else ident (bound_ctrl=false keeps old).
// ctrl: row_shr:1/2/4/8 = 0x111/0x112/0x114/0x118, row_bcast15 = 0x142,
// row_bcast31 = 0x143, wave_shl1 = 0x130 (lane i <- i+1), wave_shr1 = 0x138 (i <- i-1).
template<int CTRL, int RMASK>
__device__ __forceinline__ float dpp_f(float ident, float x) {
    return __int_as_float(__builtin_amdgcn_update_dpp(
        __float_as_int(ident), __float_as_int(x), CTRL, RMASK, 0xF, false));
}
template<int CTRL, int RMASK>
__device__ __forceinline__ int dpp_i(int ident, int x) {
    return __builtin_amdgcn_update_dpp(ident, x, CTRL, RMASK, 0xF, false);
}

__device__ __forceinline__ float zof(int k) {   // iter-0 analytic z grid
    return 0.2f + 1.8f * ((float)k * (1.0f / 127.0f));
}

struct Ray { float ox, oy, oz, dx, dy, dz; };

__device__ __forceinline__ float sdf_at(const Ray& rr, float t) {
    float px = fminf(fmaxf(rr.ox + rr.dx * t, -1.f), 1.f);
    float py = fminf(fmaxf(rr.oy + rr.dy * t, -1.f), 1.f);
    float pz = fminf(fmaxf(rr.oz + rr.dz * t, -1.f), 1.f);
    return sqrtf(px * px + py * py + pz * pz) - 0.5f;
}

template<int IT>
__device__ __forceinline__ void run_iter(float* __restrict__ z, float* __restrict__ s,
                                         float* __restrict__ cdf, int* __restrict__ sampK,
                                         float* __restrict__ outr, const int lane, const Ray rr)
{
    constexpr int  N = 128 + 32 * IT;   // current element count
    constexpr int  M = N - 1;           // interval count
    constexpr int  R = (M + 63) >> 6;   // per-lane elements: 2,3,3,4
    constexpr bool LAST  = (IT == 3);
    constexpr bool FIRST = (IT == 0);
    const float c1 = -(float)(64 << IT) * 1.44269504f;   // A = 2^(c1*pe) = e^(-pe*inv_s)
    const int k0 = lane * R;

    // ---- owned elements (analytic on iter 0; vectorized LDS otherwise) + right neighbor ----
    float ez[R], es[R], zend, send;
    if constexpr (FIRST) {
        #pragma unroll
        for (int r = 0; r < R; ++r) { ez[r] = zof(k0 + r); es[r] = sdf_at(rr, ez[r]); }
        zend = zof(k0 + R);
        send = dpp_f<0x130, 0xF>(0.f, es[0]);
    } else {
        if constexpr (R == 2) {
            float2 v = *(const float2*)(z + k0); ez[0] = v.x; ez[1] = v.y;
            float2 u = *(const float2*)(s + k0); es[0] = u.x; es[1] = u.y;
        } else if constexpr (R == 4) {
            float4 v = *(const float4*)(z + k0); ez[0]=v.x; ez[1]=v.y; ez[2]=v.z; ez[3]=v.w;
            float4 u = *(const float4*)(s + k0); es[0]=u.x; es[1]=u.y; es[2]=u.z; es[3]=u.w;
        } else {
            #pragma unroll
            for (int r = 0; r < R; ++r) { ez[r] = z[k0 + r]; es[r] = s[k0 + r]; }
        }
        zend = dpp_f<0x130, 0xF>(0.f, ez[0]);
        send = dpp_f<0x130, 0xF>(0.f, es[0]);
    }

    // ---- cos_val once per interval; prev_cos by register/DPP roll ----
    float ck[R];
    #pragma unroll
    for (int r = 0; r < R; ++r) {
        const float zk1 = (r == R - 1) ? zend : ez[(r + 1) % R];
        const float sk1 = (r == R - 1) ? send : es[(r + 1) % R];
        ck[r] = __fdividef(sk1 - es[r], zk1 - ez[r] + 1e-5f);
    }
    const float ckprv = dpp_f<0x138, 0xF>(0.f, ck[R - 1]);  // lane0 -> 0 (k=0 case)

    // ---- alpha per interval (algebraic sigmoid form: 2 exp + 1 div) ----
    float a_[R], q_[R];
    #pragma unroll
    for (int r = 0; r < R; ++r) {
        const int  k  = k0 + r;
        const bool iv = (k < M);
        const float zk1 = (r == R - 1) ? zend : ez[(r + 1) % R];
        const float sk1 = (r == R - 1) ? send : es[(r + 1) % R];
        const float cosp = (r == 0) ? ckprv : ck[r - 1];
        float cv = fminf(fminf(cosp, ck[r]), 0.0f);
        cv = fmaxf(cv, -1000.0f);
        const float mid = 0.5f * (es[r] + sk1);
        const float hd  = 0.5f * (zk1 - ez[r]);
        const float pe  = mid - cv * hd;
        const float ne  = mid + cv * hd;
        // A = e^{-pe*inv_s}, B = e^{-ne*inv_s}; clamp exponent so A,B <= 2^43 (no inf)
        const float A = __builtin_amdgcn_exp2f(fminf(c1 * pe, 43.0f));
        const float B = __builtin_amdgcn_exp2f(fminf(c1 * ne, 43.0f));
        const float A1 = 1.0f + A, B1 = 1.0f + B;
        const float prod = A1 * B1;
        const float num = (B - A) + 1e-5f * prod;   // = (pc - nc + eps) * prod
        const float den = B1 + 1e-5f * prod;        // = (pc + eps) * prod
        const float al  = __fdividef(num, den);
        a_[r] = iv ? al : 0.0f;
        q_[r] = iv ? ((1.0f - al) + 1e-7f) : 1.0f;
    }

    // ---- exclusive transmittance cumprod (DPP wave scan, pure VALU) ----
    float P = q_[0];
    #pragma unroll
    for (int r = 1; r < R; ++r) P *= q_[r];
    float incP = P;
    incP *= dpp_f<0x111, 0xF>(1.f, incP);
    incP *= dpp_f<0x112, 0xF>(1.f, incP);
    incP *= dpp_f<0x114, 0xF>(1.f, incP);
    incP *= dpp_f<0x118, 0xF>(1.f, incP);
    incP *= dpp_f<0x142, 0xA>(1.f, incP);
    incP *= dpp_f<0x143, 0xC>(1.f, incP);
    float T = dpp_f<0x138, 0xF>(1.f, incP);

    // ---- weights + exclusive sum scan -> cdf in registers ----
    float wv_[R], L = 0.f;
    #pragma unroll
    for (int r = 0; r < R; ++r) {
        const bool iv = (k0 + r < M);
        wv_[r] = iv ? (a_[r] * T + 1e-5f) : 0.f;
        L += wv_[r];
        T *= q_[r];
    }
    float incL = L;
    incL += dpp_f<0x111, 0xF>(0.f, incL);
    incL += dpp_f<0x112, 0xF>(0.f, incL);
    incL += dpp_f<0x114, 0xF>(0.f, incL);
    incL += dpp_f<0x118, 0xF>(0.f, incL);
    incL += dpp_f<0x142, 0xA>(0.f, incL);
    incL += dpp_f<0x143, 0xC>(0.f, incL);
    const float S    = __shfl(incL, 63, 64);
    const float excL = dpp_f<0x138, 0xF>(0.f, incL);
    const float invS = 1.0f / S;

    float cdfe[R];   // cdf[k0+r]
    int   cm[R];     // #{samples with u < cdf[k0+r]} = shift of old elem k0+r
    float run = excL;
    #pragma unroll
    for (int r = 0; r < R; ++r) {
        cdfe[r] = run * invS;
        // #{j: (2j+1)/64 < c} = ceil(32c - 0.5); c in [0,1] -> already in [0,32]
        cm[r] = (int)ceilf(fmaf(cdfe[r], 32.0f, -0.5f));
        run += wv_[r];
    }
    const int cmend = dpp_i<0x130, 0xF>(32, cm[0]);

    // ---- publish cdf (vectorized) + run-start marks (one store per nonempty interval) ----
    if constexpr (R == 2) {
        *(float2*)(cdf + k0) = make_float2(cdfe[0], cdfe[1]);
    } else if constexpr (R == 4) {
        *(float4*)(cdf + k0) = make_float4(cdfe[0], cdfe[1], cdfe[2], cdfe[3]);
    } else {
        #pragma unroll
        for (int r = 0; r < R; ++r) cdf[k0 + r] = cdfe[r];
    }
    #pragma unroll
    for (int r = 0; r < R; ++r) {
        const int k   = k0 + r;
        const int jlo = cm[r];
        const int jhi = (r == R - 1) ? cmend : cm[(r + 1) % R];
        if (k < M && jhi > jlo) sampK[jlo] = k;   // distinct jlo across nonempty intervals
    }
    wave_fence();   // marks+cdf visible before gather

    // ---- lane-parallel sampling: DPP max-scan inverts marks -> interval per sample ----
    float nz = 0.f, ns = 0.f; int pos = 0;
    const bool have = (lane < 32);
    if (have) {
        int m = sampK[lane];
        m = max(m, dpp_i<0x111, 0xF>(-1, m));
        m = max(m, dpp_i<0x112, 0xF>(-1, m));
        m = max(m, dpp_i<0x114, 0xF>(-1, m));
        m = max(m, dpp_i<0x118, 0xF>(-1, m));
        m = max(m, dpp_i<0x142, 0xA>(-1, m));
        const int kk = m;
        const float cl = cdf[kk], ch = cdf[kk + 1];
        float zk, zk1;
        if constexpr (FIRST) { zk = zof(kk); zk1 = zof(kk + 1); }
        else                 { zk = z[kk];   zk1 = z[kk + 1];   }
        float denom = ch - cl;
        denom = (denom < 1e-5f) ? 1.0f : denom;
        const float u = (float)(2 * lane + 1) * 0.015625f;
        nz  = zk + __fdividef(u - cl, denom) * (zk1 - zk);
        pos = kk + 1 + lane;   // rank among old + stable index among new
        if constexpr (!LAST) ns = sdf_at(rr, nz);
    }
    if constexpr (!LAST && !FIRST) wave_fence();   // gather's z reads drained before scatter

    // ---- scatter old (closed-form shift) + place new ----
    #pragma unroll
    for (int r = 0; r < R; ++r) {
        const int k = k0 + r;
        if (k < N) {
            const int p = k + cm[r];
            if constexpr (LAST) { outr[p] = ez[r]; }
            else                { z[p] = ez[r]; s[p] = es[r]; }
        }
    }
    if (have) {
        if constexpr (LAST) { outr[pos] = nz; }
        else                { z[pos] = nz; s[pos] = ns; }
    }
    if constexpr (!LAST) {
        if (have) sampK[lane] = -1;   // re-init marks for next iteration
        wave_fence();
    }
}

__global__ __launch_bounds__(RPB * 64) void neus_kernel(
    const float* __restrict__ rays_o, const float* __restrict__ rays_d,
    float* __restrict__ out, int nrays)
{
    __shared__ __align__(16) float zS[RPB][256];
    __shared__ __align__(16) float sS[RPB][256];
    __shared__ __align__(16) float cdfS[RPB][256];
    __shared__ __align__(16) int   kS[RPB][32];

    const int w    = threadIdx.x >> 6;
    const int lane = threadIdx.x & 63;
    const int ray  = blockIdx.x * RPB + w;
    if (ray >= nrays) return;   // safe: no block-wide barriers anywhere

    float* z    = zS[w];
    float* s    = sS[w];
    float* cdf  = cdfS[w];
    int*   samp = kS[w];

    Ray rr;
    rr.ox = rays_o[ray * 3 + 0]; rr.oy = rays_o[ray * 3 + 1]; rr.oz = rays_o[ray * 3 + 2];
    float rx = rays_d[ray * 3 + 0], ry = rays_d[ray * 3 + 1], rz = rays_d[ray * 3 + 2];
    float inv = __fdividef(1.0f, sqrtf(rx * rx + ry * ry + rz * rz) + 1e-8f);
    rr.dx = rx * inv; rr.dy = ry * inv; rr.dz = rz * inv;

    if (lane < 32) samp[lane] = -1;   // drained by iter0's publish fence

    float* outr = out + (size_t)ray * 256;
    run_iter<0>(z, s, cdf, samp, outr, lane, rr);   // fully analytic inputs (no LDS init pass)
    run_iter<1>(z, s, cdf, samp, outr, lane, rr);
    run_iter<2>(z, s, cdf, samp, outr, lane, rr);
    run_iter<3>(z, s, cdf, samp, outr, lane, rr);
}

extern "C" void kernel_launch(void* const* d_in, const int* in_sizes, int n_in,
                              void* d_out, int out_size, void* d_ws, size_t ws_size,
                              hipStream_t stream) {
    const float* rays_o = (const float*)d_in[0];
    const float* rays_d = (const float*)d_in[1];
    float* out = (float*)d_out;
    const int nrays = in_sizes[0] / 3;
    const int blocks = (nrays + RPB - 1) / RPB;
    neus_kernel<<<blocks, RPB * 64, 0, stream>>>(rays_o, rays_d, out, nrays);
}

// Round 6
// 100.890 us; speedup vs baseline: 4.2492x; 1.2997x over previous
//
#include <hip/hip_runtime.h>
#include <math.h>

#define WPB 4                 // waves per block
#define RPB (WPB * 2)         // 2 rays per wave (32 lanes each) -> 8 rays/block

// All per-ray LDS is touched only by its own wave (both halves belong to the wave).
__device__ __forceinline__ void wave_fence() {
    asm volatile("s_waitcnt lgkmcnt(0)" ::: "memory");
    __builtin_amdgcn_wave_barrier();
}

// DPP: dest = src[perm] where source lane valid, else ident.
// row_shr:1/2/4/8 = 0x111/0x112/0x114/0x118, row_bcast15 = 0x142,
// wave_shl1 = 0x130 (lane i <- i+1), wave_shr1 = 0x138 (lane i <- i-1).
template<int CTRL, int RMASK>
__device__ __forceinline__ float dpp_f(float ident, float x) {
    return __int_as_float(__builtin_amdgcn_update_dpp(
        __float_as_int(ident), __float_as_int(x), CTRL, RMASK, 0xF, false));
}
template<int CTRL, int RMASK>
__device__ __forceinline__ int dpp_i(int ident, int x) {
    return __builtin_amdgcn_update_dpp(ident, x, CTRL, RMASK, 0xF, false);
}

// 32-lane (per wave-half) inclusive scans: 4 row-shr steps + bcast15 into rows 1,3
__device__ __forceinline__ float scan32_mul(float x) {
    x *= dpp_f<0x111, 0xF>(1.f, x);
    x *= dpp_f<0x112, 0xF>(1.f, x);
    x *= dpp_f<0x114, 0xF>(1.f, x);
    x *= dpp_f<0x118, 0xF>(1.f, x);
    x *= dpp_f<0x142, 0xA>(1.f, x);
    return x;
}
__device__ __forceinline__ float scan32_add(float x) {
    x += dpp_f<0x111, 0xF>(0.f, x);
    x += dpp_f<0x112, 0xF>(0.f, x);
    x += dpp_f<0x114, 0xF>(0.f, x);
    x += dpp_f<0x118, 0xF>(0.f, x);
    x += dpp_f<0x142, 0xA>(0.f, x);
    return x;
}
__device__ __forceinline__ int scan32_max(int x) {
    x = max(x, dpp_i<0x111, 0xF>(-1, x));
    x = max(x, dpp_i<0x112, 0xF>(-1, x));
    x = max(x, dpp_i<0x114, 0xF>(-1, x));
    x = max(x, dpp_i<0x118, 0xF>(-1, x));
    x = max(x, dpp_i<0x142, 0xA>(-1, x));
    return x;
}
// broadcast lane 31 of each 32-half (ds_swizzle bit-mode: and=0, or=0x1F)
__device__ __forceinline__ float bcast31h(float x) {
    return __int_as_float(__builtin_amdgcn_ds_swizzle(__float_as_int(x), 0x03E0));
}

__device__ __forceinline__ float zof(int k) {   // iter-0 analytic z grid
    return 0.2f + 1.8f * ((float)k * (1.0f / 127.0f));
}

struct Ray { float ox, oy, oz, dx, dy, dz; };

__device__ __forceinline__ float sdf_at(const Ray& rr, float t) {
    float px = fminf(fmaxf(rr.ox + rr.dx * t, -1.f), 1.f);
    float py = fminf(fmaxf(rr.oy + rr.dy * t, -1.f), 1.f);
    float pz = fminf(fmaxf(rr.oz + rr.dz * t, -1.f), 1.f);
    return sqrtf(px * px + py * py + pz * pz) - 0.5f;
}

template<int IT>
__device__ __forceinline__ void run_iter(float2* __restrict__ zs, float* __restrict__ cdf,
                                         int* __restrict__ mk, float* __restrict__ outr,
                                         const int l, const Ray rr)
{
    constexpr int  N = 128 + 32 * IT;   // element count: 128,160,192,224
    constexpr int  M = N - 1;           // interval count
    constexpr int  R = N / 32;          // per-lane elements: 4,5,6,7 (exact!)
    constexpr bool LAST  = (IT == 3);
    constexpr bool FIRST = (IT == 0);
    const float c1 = -(float)(64 << IT) * 1.44269504f;   // A = 2^(c1*pe) = e^(-pe*inv_s)
    const int k0 = l * R;

    // ---- owned elements (analytic on iter 0; packed LDS float2 otherwise) ----
    float ez[R], es[R];
    if constexpr (FIRST) {
        #pragma unroll
        for (int r = 0; r < R; ++r) { ez[r] = zof(k0 + r); es[r] = sdf_at(rr, ez[r]); }
    } else {
        #pragma unroll
        for (int r = 0; r < R; ++r) { float2 v = zs[k0 + r]; ez[r] = v.x; es[r] = v.y; }
    }
    // right neighbor: next lane's first element (lane 31 of a half: unused, since
    // its top interval k0+R-1 = M is out of range by construction)
    const float zend = dpp_f<0x130, 0xF>(0.f, ez[0]);
    const float send = dpp_f<0x130, 0xF>(0.f, es[0]);

    // ---- cos of my last interval -> prev_cos for next lane's r=0 (carry the rest) ----
    const float ckL = __fdividef(send - es[R - 1], zend - ez[R - 1] + 1e-5f);
    float cosp = dpp_f<0x138, 0xF>(0.f, ckL);
    cosp = (l == 0) ? 0.f : cosp;                 // reference: prev_cos = 0 at k = 0

    // ---- alpha per interval (algebraic sigmoid: 2 exp2 + 1 div) -> q only ----
    float q[R];
    #pragma unroll
    for (int r = 0; r < R; ++r) {
        const float zk1 = (r == R - 1) ? zend : ez[r + 1];
        const float sk1 = (r == R - 1) ? send : es[r + 1];
        const float ckr = __fdividef(sk1 - es[r], zk1 - ez[r] + 1e-5f);
        float cv = fminf(fminf(cosp, ckr), 0.0f);
        cv = fmaxf(cv, -1000.0f);
        const float mid = 0.5f * (es[r] + sk1);
        const float hd  = 0.5f * (zk1 - ez[r]);
        const float A = __builtin_amdgcn_exp2f(fminf(c1 * (mid - cv * hd), 43.0f));
        const float B = __builtin_amdgcn_exp2f(fminf(c1 * (mid + cv * hd), 43.0f));
        const float A1 = 1.0f + A, B1 = 1.0f + B;
        const float prod = A1 * B1;
        const float al = __fdividef((B - A) + 1e-5f * prod, B1 + 1e-5f * prod);
        float qr = (1.0f - al) + 1e-7f;
        if (r == R - 1) qr = (l == 31) ? 1.0f : qr;   // only invalid interval: (31, R-1)
        q[r] = qr;
        cosp = ckr;
    }

    // ---- exclusive transmittance cumprod (per-half DPP scan) ----
    float P = q[0];
    #pragma unroll
    for (int r = 1; r < R; ++r) P *= q[r];
    const float incP = scan32_mul(P);
    float T = dpp_f<0x138, 0xF>(1.f, incP);
    T = (l == 0) ? 1.0f : T;

    // ---- weights (recover a from q) + exclusive sum scan ----
    float wv[R], L = 0.f;
    #pragma unroll
    for (int r = 0; r < R; ++r) {
        const float a = (1.0f + 1e-7f) - q[r];
        float w_ = fmaf(a, T, 1e-5f);
        if (r == R - 1) w_ = (l == 31) ? 0.f : w_;
        wv[r] = w_;
        L += w_;
        T *= q[r];
    }
    const float incL = scan32_add(L);
    const float S = bcast31h(incL);
    float excL = dpp_f<0x138, 0xF>(0.f, incL);
    excL = (l == 0) ? 0.f : excL;
    const float invS = 1.0f / S;

    // ---- cdf publish + closed-form sample counts cm[r] = #{j: u_j < cdf[k0+r]} ----
    int cm[R];
    float run = excL;
    #pragma unroll
    for (int r = 0; r < R; ++r) {
        const float cdfv = run * invS;
        cdf[k0 + r] = cdfv;
        cm[r] = (int)ceilf(fmaf(cdfv, 32.0f, -0.5f));   // cdf in [0,1] -> already in [0,32]
        run += wv[r];
    }
    const int cmend = dpp_i<0x130, 0xF>(32, cm[0]);      // lane31: unused (guarded)

    // ---- run-start marks: one store per nonempty interval ----
    #pragma unroll
    for (int r = 0; r < R; ++r) {
        const int jlo = cm[r];
        const int jhi = (r == R - 1) ? cmend : cm[r + 1];
        bool ne = (jhi > jlo);
        if (r == R - 1) ne = ne && (l != 31);
        if (ne) mk[jlo] = k0 + r;
    }
    wave_fence();   // marks + cdf visible before gather

    // ---- lane-parallel sampling: ALL 64 lanes (32 samples per ray half) ----
    const int kk = scan32_max(mk[l]);
    const float cl = cdf[kk], ch = cdf[kk + 1];
    float zk, zk1;
    if constexpr (FIRST) { zk = zof(kk); zk1 = zof(kk + 1); }
    else                 { zk = zs[kk].x; zk1 = zs[kk + 1].x; }
    float denom = ch - cl;
    denom = (denom < 1e-5f) ? 1.0f : denom;
    const float u = (float)(2 * l + 1) * 0.015625f;
    const float nz = fmaf(__fdividef(u - cl, denom), zk1 - zk, zk);
    const int pos = kk + 1 + l;   // rank among old + stable index among new
    float ns = 0.f;
    if constexpr (!LAST) ns = sdf_at(rr, nz);

    if constexpr (!LAST && !FIRST) wave_fence();   // gather's zs reads drained before scatter

    // ---- in-place scatter: old elems shift by cm[r]; new sample at pos ----
    #pragma unroll
    for (int r = 0; r < R; ++r) {
        const int p = k0 + r + cm[r];
        if constexpr (LAST) { outr[p] = ez[r]; }
        else                { zs[p] = make_float2(ez[r], es[r]); }
    }
    if constexpr (LAST) { outr[pos] = nz; }
    else                { zs[pos] = make_float2(nz, ns); }

    if constexpr (!LAST) {
        mk[l] = -1;    // re-init marks (same-lane same-address DS ops are ordered)
        wave_fence();
    }
}

__global__ __launch_bounds__(WPB * 64) void neus_kernel(
    const float* __restrict__ rays_o, const float* __restrict__ rays_d,
    float* __restrict__ out, int nrays)
{
    __shared__ __align__(16) float2 zsS[RPB][224];
    __shared__ __align__(16) float  cdfS[RPB][224];
    __shared__               int    mkS[RPB][32];

    const int tid = threadIdx.x;
    const int rb  = tid >> 5;        // ray slot within block (one per 32-lane half)
    const int l   = tid & 31;        // lane within ray
    const int ray = blockIdx.x * RPB + rb;
    if (ray >= nrays) return;        // safe: no block-wide barriers anywhere

    float2* zs  = zsS[rb];
    float*  cdf = cdfS[rb];
    int*    mk  = mkS[rb];

    Ray rr;
    rr.ox = rays_o[ray * 3 + 0]; rr.oy = rays_o[ray * 3 + 1]; rr.oz = rays_o[ray * 3 + 2];
    float rx = rays_d[ray * 3 + 0], ry = rays_d[ray * 3 + 1], rz = rays_d[ray * 3 + 2];
    float inv = __fdividef(1.0f, sqrtf(rx * rx + ry * ry + rz * rz) + 1e-8f);
    rr.dx = rx * inv; rr.dy = ry * inv; rr.dz = rz * inv;

    mk[l] = -1;   // drained by iter0's publish fence

    float* outr = out + (size_t)ray * 256;
    run_iter<0>(zs, cdf, mk, outr, l, rr);   // fully analytic inputs
    run_iter<1>(zs, cdf, mk, outr, l, rr);
    run_iter<2>(zs, cdf, mk, outr, l, rr);
    run_iter<3>(zs, cdf, mk, outr, l, rr);
}

extern "C" void kernel_launch(void* const* d_in, const int* in_sizes, int n_in,
                              void* d_out, int out_size, void* d_ws, size_t ws_size,
                              hipStream_t stream) {
    const float* rays_o = (const float*)d_in[0];
    const float* rays_d = (const float*)d_in[1];
    float* out = (float*)d_out;
    const int nrays = in_sizes[0] / 3;
    const int blocks = (nrays + RPB - 1) / RPB;
    neus_kernel<<<blocks, WPB * 64, 0, stream>>>(rays_o, rays_d, out, nrays);
}